// Round 10
// baseline (160.978 us; speedup 1.0000x reference)
//
#include <hip/hip_runtime.h>
#include <hip/hip_bf16.h>

// SingleAttention: q/k/v = X@W+b (fp32 in), out = softmax(q k^T/16) v, fp32 out.
// B=8 S=2048 D_IN=512 D_K=D_V=256.
// ws: EXACTLY 16 MB: ks = 8 MB of [b][64 tiles][16KB swizzled K-tile image],
//                    vt = 8 MB of [b][64 tiles][16KB swizzled V^T-tile image].
// Tile image K: elem (r<32, d<256) at byte (r*512 + d*2) ^ ((r&7)<<4).
// Tile image V^T: elem (dv<256, kv<32) at byte (dv*64 + kv*2) ^ ((dv&7)<<4).
// Q (bf16, scaled 1/16) stashed in first 512B of each d_out row (stride 512
// shorts); each attn block reads only its own rows then overwrites them.

typedef __attribute__((ext_vector_type(4))) float f32x4;
typedef __attribute__((ext_vector_type(8))) short s16x8;
typedef __attribute__((ext_vector_type(4))) short s16x4;
typedef unsigned int u32;

static __device__ __forceinline__ short f2bf(float x) {
  __hip_bfloat16 h = __float2bfloat16(x);
  return *reinterpret_cast<short*>(&h);
}
static __device__ __forceinline__ u32 pack2bf(float lo, float hi) {
  return (u32)(unsigned short)f2bf(lo) | ((u32)(unsigned short)f2bf(hi) << 16);
}
static __device__ __forceinline__ void gload16(const void* g, void* l) {
  __builtin_amdgcn_global_load_lds(
      (const __attribute__((address_space(1))) u32*)g,
      (__attribute__((address_space(3))) u32*)l, 16, 0, 0);
}

// Projection: P[16384,256] = X @ W + b -> bf16. Tile 64 rows x 256 cols so X
// is fetched from HBM exactly once. Grid 768 = 256 m-tiles x 3 z.
// z=0 -> qs (scaled 1/16, row stride 512); z=1 -> ks images; z=2 -> vt images.
__global__ __launch_bounds__(256) void proj3(
    const float* __restrict__ q_in, const float* __restrict__ k_in,
    const float* __restrict__ v_in, const float* __restrict__ bq,
    const float* __restrict__ bk, const float* __restrict__ bv,
    const float* __restrict__ Wq, const float* __restrict__ Wk,
    const float* __restrict__ Wv, short* __restrict__ qs,
    char* __restrict__ ks, char* __restrict__ vt) {
  const int bid = blockIdx.x;
  const int z = bid % 3;
  const int m0 = (bid / 3) * 64;
  const float* X = z == 0 ? q_in : z == 1 ? k_in : v_in;
  const float* W = z == 0 ? Wq : z == 1 ? Wk : Wv;
  const float* bias = z == 0 ? bq : z == 1 ? bk : bv;
  const float sc = z == 0 ? 0.0625f : 1.0f;

  __shared__ short As[64][40];
  __shared__ short Bs[256][40];

  const int tid = threadIdx.x;
  const int lane = tid & 63;
  const int wid = tid >> 6;
  const int wr = wid >> 1, wc = wid & 1;  // wave tile: rows wr*32, cols wc*128
  const int g = lane >> 4, c = lane & 15;

  f32x4 acc[2][8];
#pragma unroll
  for (int m = 0; m < 2; m++)
#pragma unroll
    for (int n = 0; n < 8; n++) acc[m][n] = (f32x4)0.0f;

  const int arow = tid >> 2, aseg = tid & 3;  // A: 64 rows x 32 fp32
  const int bn = tid;                         // B: 256 cols x 32 k

  for (int kt = 0; kt < 16; ++kt) {
    const int k0 = kt * 32;
    const float* ap = &X[(m0 + arow) * 512 + k0 + aseg * 8];
    f32x4 a0 = *(const f32x4*)(ap + 0);
    f32x4 a1 = *(const f32x4*)(ap + 4);
    float wv[32];
#pragma unroll
    for (int j = 0; j < 32; j++) wv[j] = W[(k0 + j) * 256 + bn] * sc;
    __syncthreads();  // prev frag reads done
    s16x8 ac;
#pragma unroll
    for (int i = 0; i < 4; i++) {
      ac[i] = f2bf(a0[i]);
      ac[i + 4] = f2bf(a1[i]);
    }
    *(s16x8*)&As[arow][aseg * 8] = ac;
#pragma unroll
    for (int s = 0; s < 4; s++) {
      s16x8 w8;
#pragma unroll
      for (int j = 0; j < 8; j++) w8[j] = f2bf(wv[s * 8 + j]);
      *(s16x8*)&Bs[bn][s * 8] = w8;
    }
    __syncthreads();
    s16x8 af[2], bfr[8];
#pragma unroll
    for (int m = 0; m < 2; m++)
      af[m] = *(const s16x8*)&As[wr * 32 + m * 16 + c][g * 8];
#pragma unroll
    for (int n = 0; n < 8; n++)
      bfr[n] = *(const s16x8*)&Bs[wc * 128 + n * 16 + c][g * 8];
#pragma unroll
    for (int m = 0; m < 2; m++)
#pragma unroll
      for (int n = 0; n < 8; n++)
        acc[m][n] = __builtin_amdgcn_mfma_f32_16x16x32_bf16(af[m], bfr[n],
                                                            acc[m][n], 0, 0, 0);
  }

  float bv8[8];
#pragma unroll
  for (int n = 0; n < 8; n++) bv8[n] = bias[wc * 128 + n * 16 + c] * sc;

  if (z == 0) {
#pragma unroll
    for (int m = 0; m < 2; m++) {
      const int row0 = m0 + wr * 32 + m * 16 + g * 4;
#pragma unroll
      for (int n = 0; n < 8; n++) {
        const int col = wc * 128 + n * 16 + c;
#pragma unroll
        for (int r = 0; r < 4; r++)
          qs[(row0 + r) * 512 + col] = f2bf(acc[m][n][r] + bv8[n]);
      }
    }
  } else if (z == 1) {
#pragma unroll
    for (int m = 0; m < 2; m++) {
      const int row0 = m0 + wr * 32 + m * 16 + g * 4;
#pragma unroll
      for (int n = 0; n < 8; n++) {
        const int col = wc * 128 + n * 16 + c;
#pragma unroll
        for (int r = 0; r < 4; r++) {
          const int rowg = row0 + r;
          const int bb = rowg >> 11, s = rowg & 2047;
          const int tt = s >> 5, rr = s & 31;
          const u32 off = (u32)(rr * 512 + col * 2) ^ ((u32)(rr & 7) << 4);
          *(short*)(ks + ((size_t)(bb * 64 + tt) << 14) + off) =
              f2bf(acc[m][n][r] + bv8[n]);
        }
      }
    }
  } else {
#pragma unroll
    for (int m = 0; m < 2; m++) {
      const int row0 = m0 + wr * 32 + m * 16 + g * 4;  // global s (mult of 4)
      const int bb = row0 >> 11, s = row0 & 2047;
      const int tt = s >> 5, kvl = s & 31;
#pragma unroll
      for (int n = 0; n < 8; n++) {
        const int col = wc * 128 + n * 16 + c;  // dv
        s16x4 pk;
#pragma unroll
        for (int r = 0; r < 4; r++) pk[r] = f2bf(acc[m][n][r] + bv8[n]);
        const u32 off = (u32)(col * 64 + kvl * 2) ^ ((u32)(col & 7) << 4);
        *(s16x4*)(vt + ((size_t)(bb * 64 + tt) << 14) + off) = pk;
      }
    }
  }
}

// Flash attention. Flat grid 256: b = bid&7 (XCD-local batch), q0=(bid>>3)*64.
// 1024 threads = 16 waves: grp = wid>>2 (kv quarter: 16 tiles of KVBLK=32),
// wq = wid&3 (16 q-rows). Single-buffered global_load_lds staging per group
// (K/V images L2-resident -> short DMA latency, hidden by 4 waves/SIMD).
// Swapped QK^T lane-local softmax; defer-max; 4-way LDS merge at end.
__global__ __launch_bounds__(1024) void attn_fused(
    const short* __restrict__ qs, const char* __restrict__ ksb,
    const char* __restrict__ vtb, float* __restrict__ out) {
  const int bid = blockIdx.x;
  const int b = bid & 7;
  const int q0 = (bid >> 3) * 64;

  // LDS carve (153600 B):
  //   0       stage: grp*32768 + {0: K 16KB, 16384: V 16KB}    (131072 B)
  //   131072  Ps: wid*1280, [16 q][40 shorts]                  (20480 B)
  //   151552  Ml: [4 grp][64 q][2] f32                         (2048 B)
  //   merge overlay: Om [64][260] f32 at offset 0 (66560 B, loop done)
  __shared__ __align__(16) char smem[153600];

  const int tid = threadIdx.x;
  const int lane = tid & 63;
  const int wid = tid >> 6;    // 0..15
  const int grp = wid >> 2;    // kv quarter
  const int wq = wid & 3;      // q quarter (16 rows)
  const int gtid = tid & 255;  // within group
  const int g = lane >> 4, c = lane & 15;

  const char* ktiles = ksb + ((size_t)b << 20);  // 64 tiles * 16KB = 1MB
  const char* vtiles = vtb + ((size_t)b << 20);

  char* gbase = smem + grp * 32768;
  short* Ps = (short*)(smem + 131072 + wid * 1280);  // [16][40]
  float* Mlf = (float*)(smem + 151552);              // [4][64][2]

  // hoist Q fragments (bf16, pre-scaled by 1/16)
  s16x8 qf[8];
  {
    const int qrow = (b << 11) + q0 + wq * 16 + c;
#pragma unroll
    for (int d = 0; d < 8; d++)
      qf[d] = *(const s16x8*)&qs[qrow * 512 + d * 32 + g * 8];
  }

  f32x4 o[16];
#pragma unroll
  for (int f = 0; f < 16; f++) o[f] = (f32x4)0.0f;
  float m_l = -1e30f;  // running max of q-row c (this lane's row)
  float l_l = 0.f;

  const u32 xr = (u32)(c & 7) << 4;  // read-side swizzle

  auto STAGE = [&](int t) {
    const size_t toff = (size_t)(grp * 16 + t) << 14;
    const char* ksrc = ktiles + toff + gtid * 16;
    const char* vsrc = vtiles + toff + gtid * 16;
    char* kd = gbase + gtid * 16;
    char* vd = gbase + 16384 + gtid * 16;
#pragma unroll
    for (int i = 0; i < 4; i++) {
      gload16(ksrc + i * 4096, kd + i * 4096);
      gload16(vsrc + i * 4096, vd + i * 4096);
    }
  };

  STAGE(0);
  __syncthreads();  // drain prologue DMA

  for (int t = 0; t < 16; ++t) {
    const char* Kb = gbase;
    const char* Vb = gbase + 16384;

    // S^T = K Q^T (swapped): sf[nf][r] = S[q=c][kv = nf*16 + g*4 + r]
    f32x4 sf[2];
    sf[0] = (f32x4)0.0f;
    sf[1] = (f32x4)0.0f;
    __builtin_amdgcn_s_setprio(1);
#pragma unroll
    for (int d = 0; d < 8; ++d) {
      const u32 k0off = ((u32)(c * 512 + d * 64 + g * 16)) ^ xr;
      const s16x8 kf0 = *(const s16x8*)(Kb + k0off);
      const s16x8 kf1 = *(const s16x8*)(Kb + (k0off + 8192));  // rows 16..31
      sf[0] = __builtin_amdgcn_mfma_f32_16x16x32_bf16(kf0, qf[d], sf[0], 0, 0, 0);
      sf[1] = __builtin_amdgcn_mfma_f32_16x16x32_bf16(kf1, qf[d], sf[1], 0, 0, 0);
    }
    __builtin_amdgcn_s_setprio(0);

    // lane-local online softmax with defer-max (THR=8); row = c
    float mx = sf[0][0];
#pragma unroll
    for (int nf = 0; nf < 2; nf++)
#pragma unroll
      for (int r = 0; r < 4; r++) mx = fmaxf(mx, sf[nf][r]);
    mx = fmaxf(mx, __shfl_xor(mx, 16, 64));
    mx = fmaxf(mx, __shfl_xor(mx, 32, 64));
    if (__any(mx > m_l + 8.f)) {  // wave-uniform rescale
      const float mn = fmaxf(m_l, mx);
      const float scr = __expf(m_l - mn);
      m_l = mn;
      l_l *= scr;
      float so[4];
#pragma unroll
      for (int r = 0; r < 4; r++) so[r] = __shfl(scr, g * 4 + r, 64);
#pragma unroll
      for (int f = 0; f < 16; f++)
#pragma unroll
        for (int r = 0; r < 4; r++) o[f][r] *= so[r];
    }
    float sum = 0.f;
#pragma unroll
    for (int nf = 0; nf < 2; nf++)
#pragma unroll
      for (int r = 0; r < 4; r++) {
        const float p = __expf(sf[nf][r] - m_l);
        sf[nf][r] = p;
        sum += p;
      }
    sum += __shfl_xor(sum, 16, 64);
    sum += __shfl_xor(sum, 32, 64);
    l_l += sum;

    // P -> wave-private LDS packed bf16x2 (same-wave ds ordering, no barrier)
#pragma unroll
    for (int nf = 0; nf < 2; nf++) {
      const int base = c * 40 + nf * 16 + g * 4;
      *(u32*)&Ps[base] = pack2bf(sf[nf][0], sf[nf][1]);
      *(u32*)&Ps[base + 2] = pack2bf(sf[nf][2], sf[nf][3]);
    }

    // O += P V
    const s16x8 pa = *(const s16x8*)&Ps[c * 40 + g * 8];
    __builtin_amdgcn_s_setprio(1);
#pragma unroll
    for (int f = 0; f < 16; ++f) {
      const u32 voff = ((u32)((f * 16 + c) * 64 + g * 16)) ^ xr;
      const s16x8 vf = *(const s16x8*)(Vb + voff);
      o[f] = __builtin_amdgcn_mfma_f32_16x16x32_bf16(pa, vf, o[f], 0, 0, 0);
    }
    __builtin_amdgcn_s_setprio(0);

    __syncthreads();  // all LDS reads of tile t done
    if (t < 15) STAGE(t + 1);
    __syncthreads();  // compiler drains vmcnt before barrier -> tile ready
  }

  // ---- 4-way merge of kv-quarter states ----
  if (g == 0) {
    Mlf[(grp * 64 + wq * 16 + c) * 2 + 0] = m_l;
    Mlf[(grp * 64 + wq * 16 + c) * 2 + 1] = l_l;
  }
  __syncthreads();
  float eown[4], inv4[4];
#pragma unroll
  for (int r = 0; r < 4; r++) {
    const int rw = wq * 16 + g * 4 + r;
    float ms = -1e30f;
#pragma unroll
    for (int gg = 0; gg < 4; gg++) ms = fmaxf(ms, Mlf[(gg * 64 + rw) * 2]);
    float den = 0.f;
#pragma unroll
    for (int gg = 0; gg < 4; gg++)
      den += __expf(Mlf[(gg * 64 + rw) * 2] - ms) * Mlf[(gg * 64 + rw) * 2 + 1];
    eown[r] = __expf(Mlf[(grp * 64 + rw) * 2] - ms);
    inv4[r] = 1.0f / den;
  }
  float* Omf = (float*)smem;  // [64][260] overlay on stage region
  for (int gg = 0; gg < 4; ++gg) {
    if (grp == gg) {
#pragma unroll
      for (int f = 0; f < 16; f++)
#pragma unroll
        for (int r = 0; r < 4; r++) {
          const int rw = wq * 16 + g * 4 + r;
          const int idx = rw * 260 + f * 16 + c;
          const float v = eown[r] * o[f][r];
          if (gg == 0)
            Omf[idx] = v;
          else
            Omf[idx] += v;
        }
    }
    __syncthreads();
  }
  if (grp == 0) {
#pragma unroll
    for (int f = 0; f < 16; f++)
#pragma unroll
      for (int r = 0; r < 4; r++) {
        const int rw = wq * 16 + g * 4 + r;
        out[((b << 11) + q0 + rw) * 256 + f * 16 + c] =
            Omf[rw * 260 + f * 16 + c] * inv4[r];
      }
  }
}

extern "C" void kernel_launch(void* const* d_in, const int* in_sizes, int n_in,
                              void* d_out, int out_size, void* d_ws,
                              size_t ws_size, hipStream_t stream) {
  const float* q_in = (const float*)d_in[0];
  const float* k_in = (const float*)d_in[1];
  const float* v_in = (const float*)d_in[2];
  const float* Wq = (const float*)d_in[3];
  const float* bq = (const float*)d_in[4];
  const float* Wk = (const float*)d_in[5];
  const float* bk = (const float*)d_in[6];
  const float* Wv = (const float*)d_in[7];
  const float* bv = (const float*)d_in[8];
  float* out = (float*)d_out;

  char* ws = (char*)d_ws;
  short* qsb = (short*)d_out;  // Q bf16 in first 512B of each out row
  char* ksb = ws;              // 8 MB swizzled K tile images
  char* vtb = ws + (8 << 20);  // 8 MB swizzled V^T tile images

  proj3<<<dim3(768), dim3(256), 0, stream>>>(q_in, k_in, v_in, bq, bk, bv, Wq,
                                             Wk, Wv, qsb, ksb, vtb);
  attn_fused<<<dim3(256), dim3(1024), 0, stream>>>(qsb, ksb, vtb, out);
}

// Round 11
// 97.646 us; speedup vs baseline: 1.6486x; 1.6486x over previous
//
#include <hip/hip_runtime.h>
#include <hip/hip_bf16.h>

// SingleAttention: q/k/v = X@W+b (fp32 in), out = softmax(q k^T/16) v, fp32 out.
// B=8 S=2048 D_IN=512 D_K=D_V=256.
// ws: EXACTLY 16 MB: ks = 8 MB of [b][64 tiles][16KB swizzled K-tile image],
//                    vt = 8 MB of [b][64 tiles][16KB swizzled V^T-tile image].
// Tile image K: elem (r<32, d<256) at byte (r*512 + d*2) ^ ((r&7)<<4).
// Tile image V^T: elem (dv<256, kv<32) at byte (dv*64 + kv*2) ^ ((dv&7)<<4).
// Q (bf16, scaled 1/16) stashed in first 512B of each d_out row (stride 512
// shorts); each attn block reads only its own rows then overwrites them.

typedef __attribute__((ext_vector_type(4))) float f32x4;
typedef __attribute__((ext_vector_type(8))) short s16x8;
typedef __attribute__((ext_vector_type(4))) short s16x4;
typedef unsigned int u32;

static __device__ __forceinline__ short f2bf(float x) {
  __hip_bfloat16 h = __float2bfloat16(x);
  return *reinterpret_cast<short*>(&h);
}
static __device__ __forceinline__ u32 pack2bf(float lo, float hi) {
  return (u32)(unsigned short)f2bf(lo) | ((u32)(unsigned short)f2bf(hi) << 16);
}
static __device__ __forceinline__ void gload16(const void* g, void* l) {
  __builtin_amdgcn_global_load_lds(
      (const __attribute__((address_space(1))) u32*)g,
      (__attribute__((address_space(3))) u32*)l, 16, 0, 0);
}

// Projection: P[16384,256] = X @ W + b -> bf16. Tile 64 rows x 256 cols so X
// is fetched from HBM exactly once. Grid 768 = 256 m-tiles x 3 z.
// z=0 -> qs (scaled 1/16, row stride 512); z=1 -> ks images; z=2 -> vt images.
__global__ __launch_bounds__(256) void proj3(
    const float* __restrict__ q_in, const float* __restrict__ k_in,
    const float* __restrict__ v_in, const float* __restrict__ bq,
    const float* __restrict__ bk, const float* __restrict__ bv,
    const float* __restrict__ Wq, const float* __restrict__ Wk,
    const float* __restrict__ Wv, short* __restrict__ qs,
    char* __restrict__ ks, char* __restrict__ vt) {
  const int bid = blockIdx.x;
  const int z = bid % 3;
  const int m0 = (bid / 3) * 64;
  const float* X = z == 0 ? q_in : z == 1 ? k_in : v_in;
  const float* W = z == 0 ? Wq : z == 1 ? Wk : Wv;
  const float* bias = z == 0 ? bq : z == 1 ? bk : bv;
  const float sc = z == 0 ? 0.0625f : 1.0f;

  __shared__ short As[64][40];
  __shared__ short Bs[256][40];

  const int tid = threadIdx.x;
  const int lane = tid & 63;
  const int wid = tid >> 6;
  const int wr = wid >> 1, wc = wid & 1;  // wave tile: rows wr*32, cols wc*128
  const int g = lane >> 4, c = lane & 15;

  f32x4 acc[2][8];
#pragma unroll
  for (int m = 0; m < 2; m++)
#pragma unroll
    for (int n = 0; n < 8; n++) acc[m][n] = (f32x4)0.0f;

  const int arow = tid >> 2, aseg = tid & 3;  // A: 64 rows x 32 fp32
  const int bn = tid;                         // B: 256 cols x 32 k

  for (int kt = 0; kt < 16; ++kt) {
    const int k0 = kt * 32;
    const float* ap = &X[(m0 + arow) * 512 + k0 + aseg * 8];
    f32x4 a0 = *(const f32x4*)(ap + 0);
    f32x4 a1 = *(const f32x4*)(ap + 4);
    float wv[32];
#pragma unroll
    for (int j = 0; j < 32; j++) wv[j] = W[(k0 + j) * 256 + bn] * sc;
    __syncthreads();  // prev frag reads done
    s16x8 ac;
#pragma unroll
    for (int i = 0; i < 4; i++) {
      ac[i] = f2bf(a0[i]);
      ac[i + 4] = f2bf(a1[i]);
    }
    *(s16x8*)&As[arow][aseg * 8] = ac;
#pragma unroll
    for (int s = 0; s < 4; s++) {
      s16x8 w8;
#pragma unroll
      for (int j = 0; j < 8; j++) w8[j] = f2bf(wv[s * 8 + j]);
      *(s16x8*)&Bs[bn][s * 8] = w8;
    }
    __syncthreads();
    s16x8 af[2], bfr[8];
#pragma unroll
    for (int m = 0; m < 2; m++)
      af[m] = *(const s16x8*)&As[wr * 32 + m * 16 + c][g * 8];
#pragma unroll
    for (int n = 0; n < 8; n++)
      bfr[n] = *(const s16x8*)&Bs[wc * 128 + n * 16 + c][g * 8];
#pragma unroll
    for (int m = 0; m < 2; m++)
#pragma unroll
      for (int n = 0; n < 8; n++)
        acc[m][n] = __builtin_amdgcn_mfma_f32_16x16x32_bf16(af[m], bfr[n],
                                                            acc[m][n], 0, 0, 0);
  }

  float bv8[8];
#pragma unroll
  for (int n = 0; n < 8; n++) bv8[n] = bias[wc * 128 + n * 16 + c] * sc;

  if (z == 0) {
#pragma unroll
    for (int m = 0; m < 2; m++) {
      const int row0 = m0 + wr * 32 + m * 16 + g * 4;
#pragma unroll
      for (int n = 0; n < 8; n++) {
        const int col = wc * 128 + n * 16 + c;
#pragma unroll
        for (int r = 0; r < 4; r++)
          qs[(row0 + r) * 512 + col] = f2bf(acc[m][n][r] + bv8[n]);
      }
    }
  } else if (z == 1) {
#pragma unroll
    for (int m = 0; m < 2; m++) {
      const int row0 = m0 + wr * 32 + m * 16 + g * 4;
#pragma unroll
      for (int n = 0; n < 8; n++) {
        const int col = wc * 128 + n * 16 + c;
#pragma unroll
        for (int r = 0; r < 4; r++) {
          const int rowg = row0 + r;
          const int bb = rowg >> 11, s = rowg & 2047;
          const int tt = s >> 5, rr = s & 31;
          const u32 off = (u32)(rr * 512 + col * 2) ^ ((u32)(rr & 7) << 4);
          *(short*)(ks + ((size_t)(bb * 64 + tt) << 14) + off) =
              f2bf(acc[m][n][r] + bv8[n]);
        }
      }
    }
  } else {
#pragma unroll
    for (int m = 0; m < 2; m++) {
      const int row0 = m0 + wr * 32 + m * 16 + g * 4;  // global s (mult of 4)
      const int bb = row0 >> 11, s = row0 & 2047;
      const int tt = s >> 5, kvl = s & 31;
#pragma unroll
      for (int n = 0; n < 8; n++) {
        const int col = wc * 128 + n * 16 + c;  // dv
        s16x4 pk;
#pragma unroll
        for (int r = 0; r < 4; r++) pk[r] = f2bf(acc[m][n][r] + bv8[n]);
        const u32 off = (u32)(col * 64 + kvl * 2) ^ ((u32)(col & 7) << 4);
        *(s16x4*)(vt + ((size_t)(bb * 64 + tt) << 14) + off) = pk;
      }
    }
  }
}

// Flash attention (R9 structure, proven 67.6us). Flat grid 256: b = bid&7
// (XCD-local batch), q0=(bid>>3)*64. 512 threads = 8 waves: grp = wid>>2
// (kv half, 32 tiles of KVBLK=32), wq = wid&3 (16 q-rows). Per-group
// double-buffered global_load_lds staging from pre-swizzled tile images;
// XOR-swizzled ds_reads; swapped QK^T lane-local softmax; defer-max;
// one barrier per iteration.
__global__ __launch_bounds__(512, 1) void attn_fused(
    const short* __restrict__ qs, const char* __restrict__ ksb,
    const char* __restrict__ vtb, float* __restrict__ out) {
  const int bid = blockIdx.x;
  const int b = bid & 7;
  const int q0 = (bid >> 3) * 64;

  // LDS carve (141312 B):
  //   stage: grp*65536 + sel*32768 + {0: K 16KB, 16384: V 16KB}   (131072 B)
  //   Ps:    131072 + wid*1280, [16 q][40 shorts]                 (10240 B)
  //   merge overlay: Om [64][260] f32 at 0; Ml [64][2] f32 at 66560
  __shared__ __align__(16) char smem[141312];

  const int tid = threadIdx.x;
  const int lane = tid & 63;
  const int wid = tid >> 6;
  const int grp = wid >> 2;    // kv half
  const int wq = wid & 3;      // q quarter (16 rows)
  const int gtid = tid & 255;  // within group
  const int g = lane >> 4, c = lane & 15;

  const char* ktiles = ksb + ((size_t)b << 20);  // 64 tiles * 16KB = 1MB
  const char* vtiles = vtb + ((size_t)b << 20);

  char* gbase = smem + grp * 65536;
  short* Ps = (short*)(smem + 131072 + wid * 1280);  // [16][40]

  // hoist Q fragments (bf16, pre-scaled by 1/16)
  s16x8 qf[8];
  {
    const int qrow = (b << 11) + q0 + wq * 16 + c;
#pragma unroll
    for (int d = 0; d < 8; d++)
      qf[d] = *(const s16x8*)&qs[qrow * 512 + d * 32 + g * 8];
  }

  f32x4 o[16];
#pragma unroll
  for (int f = 0; f < 16; f++) o[f] = (f32x4)0.0f;
  float m_l = -1e30f;  // running max of q-row c (this lane's row)
  float l_l = 0.f;

  const u32 xr = (u32)(c & 7) << 4;  // read-side swizzle

  auto STAGE = [&](int t, int sel) {
    const size_t toff = (size_t)(grp * 32 + t) << 14;
    char* kd = gbase + sel * 32768;
    char* vd = kd + 16384;
    const char* ksrc = ktiles + toff + gtid * 16;
    const char* vsrc = vtiles + toff + gtid * 16;
#pragma unroll
    for (int i = 0; i < 4; i++) {
      gload16(ksrc + i * 4096, kd + gtid * 16 + i * 4096);
      gload16(vsrc + i * 4096, vd + gtid * 16 + i * 4096);
    }
  };

  STAGE(0, 0);
  __syncthreads();  // drain prologue stage

  for (int t = 0; t < 32; ++t) {
    const int sel = t & 1;
    if (t < 31) STAGE(t + 1, sel ^ 1);  // flies under this tile's compute

    const char* Kb = gbase + sel * 32768;
    const char* Vb = Kb + 16384;

    // S^T = K Q^T (swapped): sf[nf][r] = S[q=c][kv = nf*16 + g*4 + r]
    f32x4 sf[2];
    sf[0] = (f32x4)0.0f;
    sf[1] = (f32x4)0.0f;
    __builtin_amdgcn_s_setprio(1);
#pragma unroll
    for (int d = 0; d < 8; ++d) {
      const u32 k0off = ((u32)(c * 512 + d * 64 + g * 16)) ^ xr;
      const s16x8 kf0 = *(const s16x8*)(Kb + k0off);
      const s16x8 kf1 = *(const s16x8*)(Kb + (k0off + 8192));  // rows 16..31
      sf[0] = __builtin_amdgcn_mfma_f32_16x16x32_bf16(kf0, qf[d], sf[0], 0, 0, 0);
      sf[1] = __builtin_amdgcn_mfma_f32_16x16x32_bf16(kf1, qf[d], sf[1], 0, 0, 0);
    }
    __builtin_amdgcn_s_setprio(0);

    // lane-local online softmax with defer-max (THR=8); row = c
    float mx = sf[0][0];
#pragma unroll
    for (int nf = 0; nf < 2; nf++)
#pragma unroll
      for (int r = 0; r < 4; r++) mx = fmaxf(mx, sf[nf][r]);
    mx = fmaxf(mx, __shfl_xor(mx, 16, 64));
    mx = fmaxf(mx, __shfl_xor(mx, 32, 64));
    if (__any(mx > m_l + 8.f)) {  // wave-uniform rescale
      const float mn = fmaxf(m_l, mx);
      const float scr = __expf(m_l - mn);
      m_l = mn;
      l_l *= scr;
      float so[4];
#pragma unroll
      for (int r = 0; r < 4; r++) so[r] = __shfl(scr, g * 4 + r, 64);
#pragma unroll
      for (int f = 0; f < 16; f++)
#pragma unroll
        for (int r = 0; r < 4; r++) o[f][r] *= so[r];
    }
    float sum = 0.f;
#pragma unroll
    for (int nf = 0; nf < 2; nf++)
#pragma unroll
      for (int r = 0; r < 4; r++) {
        const float p = __expf(sf[nf][r] - m_l);
        sf[nf][r] = p;
        sum += p;
      }
    sum += __shfl_xor(sum, 16, 64);
    sum += __shfl_xor(sum, 32, 64);
    l_l += sum;

    // P -> wave-private LDS packed bf16x2 (same-wave ds ordering, no barrier)
#pragma unroll
    for (int nf = 0; nf < 2; nf++) {
      const int base = c * 40 + nf * 16 + g * 4;
      *(u32*)&Ps[base] = pack2bf(sf[nf][0], sf[nf][1]);
      *(u32*)&Ps[base + 2] = pack2bf(sf[nf][2], sf[nf][3]);
    }

    // O += P V
    const s16x8 pa = *(const s16x8*)&Ps[c * 40 + g * 8];
    __builtin_amdgcn_s_setprio(1);
#pragma unroll
    for (int f = 0; f < 16; ++f) {
      const u32 voff = ((u32)((f * 16 + c) * 64 + g * 16)) ^ xr;
      const s16x8 vf = *(const s16x8*)(Vb + voff);
      o[f] = __builtin_amdgcn_mfma_f32_16x16x32_bf16(pa, vf, o[f], 0, 0, 0);
    }
    __builtin_amdgcn_s_setprio(0);

    __syncthreads();  // drains stage(t+1) DMA + this tile's LDS reads
  }

  // ---- merge the two kv-half states and write out ----
  float(*Om)[260] = (float(*)[260])smem;          // 66560 B
  float(*Ml)[2] = (float(*)[2])(smem + 66560);    // 512 B
  float m0r[4], l0r[4];
#pragma unroll
  for (int r = 0; r < 4; r++) {
    m0r[r] = __shfl(m_l, g * 4 + r, 64);
    l0r[r] = __shfl(l_l, g * 4 + r, 64);
  }
  if (grp == 1) {
#pragma unroll
    for (int f = 0; f < 16; f++)
#pragma unroll
      for (int r = 0; r < 4; r++)
        Om[wq * 16 + g * 4 + r][f * 16 + c] = o[f][r];
    if (g == 0) {
      Ml[wq * 16 + c][0] = m_l;
      Ml[wq * 16 + c][1] = l_l;
    }
  }
  __syncthreads();
  if (grp == 0) {
    float e0v[4], e1v[4], inv[4];
#pragma unroll
    for (int r = 0; r < 4; r++) {
      const int rw = wq * 16 + g * 4 + r;
      const float m1 = Ml[rw][0], l1 = Ml[rw][1];
      const float ms = fmaxf(m0r[r], m1);
      e0v[r] = __expf(m0r[r] - ms);
      e1v[r] = __expf(m1 - ms);
      inv[r] = 1.0f / (l0r[r] * e0v[r] + l1 * e1v[r]);
    }
#pragma unroll
    for (int f = 0; f < 16; f++) {
#pragma unroll
      for (int r = 0; r < 4; r++) {
        const int rw = wq * 16 + g * 4 + r;
        out[((b << 11) + q0 + rw) * 256 + f * 16 + c] =
            (o[f][r] * e0v[r] + Om[rw][f * 16 + c] * e1v[r]) * inv[r];
      }
    }
  }
}

extern "C" void kernel_launch(void* const* d_in, const int* in_sizes, int n_in,
                              void* d_out, int out_size, void* d_ws,
                              size_t ws_size, hipStream_t stream) {
  const float* q_in = (const float*)d_in[0];
  const float* k_in = (const float*)d_in[1];
  const float* v_in = (const float*)d_in[2];
  const float* Wq = (const float*)d_in[3];
  const float* bq = (const float*)d_in[4];
  const float* Wk = (const float*)d_in[5];
  const float* bk = (const float*)d_in[6];
  const float* Wv = (const float*)d_in[7];
  const float* bv = (const float*)d_in[8];
  float* out = (float*)d_out;

  char* ws = (char*)d_ws;
  short* qsb = (short*)d_out;  // Q bf16 in first 512B of each out row
  char* ksb = ws;              // 8 MB swizzled K tile images
  char* vtb = ws + (8 << 20);  // 8 MB swizzled V^T tile images

  proj3<<<dim3(768), dim3(256), 0, stream>>>(q_in, k_in, v_in, bq, bk, bv, Wq,
                                             Wk, Wv, qsb, ksb, vtb);
  attn_fused<<<dim3(256), dim3(512), 0, stream>>>(qsb, ksb, vtb, out);
}